// Round 2
// baseline (1117.862 us; speedup 1.0000x reference)
//
#include <hip/hip_runtime.h>

// DGM forward, MI355X. bf16 MFMA 16x16x32, fp32 accum, fp32 tanh.
// R7: R5 structure restored EXACTLY (4 barriers/layer, in-place Sb via zs-trick,
//     33 KB LDS, per-gate txS reads) — R6's SRb/2-barrier restructure regressed
//     (+69 us stall) and is reverted. Kept from R6 (counter-verified neutral-to-
//     good): v_cvt_pk_bf16_f32 pack, exp2-direct tanh, G-gate 1-tanh=2*rcp.
//     NEW: __launch_bounds__(256,3). R1 showed (256,2)->128 VGPR 2 waves/SIMD
//     (occupancy-capped, 45% stall); (256,4)->64 VGPR+spill. (256,3) targets
//     ~168 total regs/wave -> 3 waves/SIMD, +50% latency hiding on a kernel
//     whose combined pipe busy is only ~55%.
//
// MFMA 16x16x32 layouts (ln = lane, q = ln>>4, c15 = ln&15):
//  A-frag: lane holds A[m=c15][k=kb*32+q*8+i], i=0..7
//  B-frag: lane holds B[k=kb*32+q*8+i][n=cblk*16+c15]
//  C/D:    lane holds C[row=q*4+ii][col=c15]
// W packed (d_ws) B-frag order per matrix: idx = (((cblk*8+kb)*64+ln)*8+i)
// LDS state swizzle: elem(r,k) -> r*256 + (((k>>3)^r)&31)*8 + (k&7)

typedef __attribute__((ext_vector_type(8))) short bf16x8;
typedef __attribute__((ext_vector_type(4))) float f32x4;

#if __has_builtin(__builtin_amdgcn_exp2f)
#define EXP2F(x) __builtin_amdgcn_exp2f(x)
#else
#define EXP2F(x) __expf((x) * 0.6931471805599453f)
#endif

__device__ __forceinline__ short f2bf(float f) {
    unsigned u = __float_as_uint(f);
    unsigned r = (u + 0x7FFFu + ((u >> 16) & 1u)) >> 16;
    return (short)r;
}
__device__ __forceinline__ float bf2f(short h) {
    return __uint_as_float(((unsigned)(unsigned short)h) << 16);
}
// packed bf16 pair via HW convert (RNE, same rounding as f2bf)
__device__ __forceinline__ unsigned cvtpk(float lo, float hi) {
    unsigned r;
    asm("v_cvt_pk_bf16_f32 %0, %1, %2" : "=v"(r) : "v"(lo), "v"(hi));
    return r;
}
// rcp(1 + e^{2x}); tanh(x) = 1 - 2*this; 1 - tanh(x) = 2*this
__device__ __forceinline__ float rcp_1pe2x(float x) {
    float e = EXP2F(x * 2.8853900817779268f);   // 2*log2(e)
    return __builtin_amdgcn_rcpf(e + 1.0f);
}
__device__ __forceinline__ float fast_tanh(float x) {
    return fmaf(-2.0f, rcp_1pe2x(x), 1.0f);
}
__device__ __forceinline__ int sw_off(int r, int k) {
    return r * 256 + ((((k >> 3) ^ r) & 31) << 3) + (k & 7);
}
__device__ __forceinline__ unsigned pk2(float a, float b) { return cvtpk(a, b); }
__device__ __forceinline__ float upk(unsigned p, int hi) {
    return __uint_as_float(hi ? (p & 0xFFFF0000u) : (p << 16));
}

// ---------------- pack weights fp32 -> bf16, B-frag order ----------------
__global__ void pack_w(const float* __restrict__ Wz, const float* __restrict__ Wg,
                       const float* __restrict__ Wr, const float* __restrict__ Wh,
                       short* __restrict__ out) {
    int idx = blockIdx.x * 256 + threadIdx.x;   // 12*65536 threads
    int mat = idx >> 16;                        // 0..11 = l*4+g
    int e   = idx & 65535;
    int l = mat >> 2, g = mat & 3;
    int i  = e & 7;
    int ln = (e >> 3) & 63;
    int kb = (e >> 9) & 7;
    int c  = e >> 12;
    int k = kb * 32 + (ln >> 4) * 8 + i;
    int n = c * 16 + (ln & 15);
    const float* W = (g == 0) ? Wz : (g == 1) ? Wg : (g == 2) ? Wr : Wh;
    out[idx] = f2bf(W[l * 65536 + k * 256 + n]);
}

// ---------------- one gate GEMM: acc = bias + X@U + In@W ----------------
__device__ __forceinline__ void gate_gemm(const short* __restrict__ In,   // LDS [32][256] swizzled
                                          const short* __restrict__ Wm,   // packed bf16 65536
                                          const float* __restrict__ U,    // [2][256] fp32
                                          const float* __restrict__ bias, // [256]
                                          const float2* __restrict__ txS, // LDS [32]
                                          int q, int c15, int w,
                                          f32x4 acc[2][4]) {
    float2 tx[8];
#pragma unroll
    for (int rb = 0; rb < 2; rb++)
#pragma unroll
        for (int ii = 0; ii < 4; ii++) tx[rb * 4 + ii] = txS[rb * 16 + q * 4 + ii];
#pragma unroll
    for (int cb = 0; cb < 4; cb++) {
        int col = (w * 4 + cb) * 16 + c15;
        float u0 = U[col], u1 = U[256 + col], bb = bias[col];
#pragma unroll
        for (int rb = 0; rb < 2; rb++)
#pragma unroll
            for (int ii = 0; ii < 4; ii++)
                acc[rb][cb][ii] = bb + tx[rb * 4 + ii].x * u0 + tx[rb * 4 + ii].y * u1;
    }
#pragma unroll
    for (int kb = 0; kb < 8; kb++) {
        bf16x8 a[2];
#pragma unroll
        for (int rb = 0; rb < 2; rb++) {
            int r = rb * 16 + c15;
            a[rb] = *(const bf16x8*)(In + r * 256 + ((((kb * 4 + q) ^ r) & 31) << 3));
        }
#pragma unroll
        for (int cb = 0; cb < 4; cb++) {
            bf16x8 b = *(const bf16x8*)(Wm + ((((w * 4 + cb) * 8 + kb) * 64 + (q * 16 + c15)) << 3));
#pragma unroll
            for (int rb = 0; rb < 2; rb++)
                acc[rb][cb] = __builtin_amdgcn_mfma_f32_16x16x32_bf16(a[rb], b, acc[rb][cb], 0, 0, 0);
        }
    }
}

// ---------------- main kernel: 32 rows/WG, 256 threads ----------------
__global__ __launch_bounds__(256, 3)
void dgm_main(const float* __restrict__ T, const float* __restrict__ X,
              const float* __restrict__ W0, const float* __restrict__ b0,
              const float* __restrict__ Uz, const float* __restrict__ Ug,
              const float* __restrict__ Ur, const float* __restrict__ Uh,
              const float* __restrict__ bz, const float* __restrict__ bg,
              const float* __restrict__ br, const float* __restrict__ bh,
              const float* __restrict__ Wf, const float* __restrict__ bfp,
              const short* __restrict__ Wp, float* __restrict__ out) {
    __shared__ __align__(16) short Sb[8192];    // 16 KB: S (holds S*R mid-layer)
    __shared__ __align__(16) short S1b[8192];   // 16 KB: S1, immutable
    __shared__ float2 txS[32];

    const int tid = threadIdx.x;
    const int w   = tid >> 6;        // 0..3
    const int ln  = tid & 63;
    const int q   = ln >> 4;
    const int c15 = ln & 15;
    const int m0  = blockIdx.x * 32;

    if (tid < 32) txS[tid] = make_float2(T[m0 + tid], X[m0 + tid]);
    __syncthreads();

    // ---- S1 = tanh(X@W0 + b0); S = S1.  One column per thread, 32 rows. ----
    {
        float w00 = W0[tid], w01 = W0[256 + tid], bb = b0[tid];
#pragma unroll 4
        for (int r = 0; r < 32; r++) {
            float2 tx = txS[r];
            short v = f2bf(fast_tanh(tx.x * w00 + tx.y * w01 + bb));
            int off = sw_off(r, tid);
            S1b[off] = v;
            Sb[off]  = v;
        }
    }
    __syncthreads();

    // register mirror of this thread's owned S elements (C-layout), packed bf16
    unsigned sreg[2][4][2];
#pragma unroll
    for (int rb = 0; rb < 2; rb++)
#pragma unroll
        for (int cb = 0; cb < 4; cb++) {
            int col = (w * 4 + cb) * 16 + c15;
#pragma unroll
            for (int p = 0; p < 2; p++) {
                unsigned lo = (unsigned short)Sb[sw_off(rb * 16 + q * 4 + 2 * p,     col)];
                unsigned hi = (unsigned short)Sb[sw_off(rb * 16 + q * 4 + 2 * p + 1, col)];
                sreg[rb][cb][p] = lo | (hi << 16);
            }
        }

    // ---- layers ----
    for (int l = 0; l < 3; l++) {
        const short* Wzp = Wp + (l * 4 + 0) * 65536;
        const short* Wgp = Wp + (l * 4 + 1) * 65536;
        const short* Wrp = Wp + (l * 4 + 2) * 65536;
        const short* Whp = Wp + (l * 4 + 3) * 65536;

        f32x4 acc[2][4];
        unsigned zsp[2][4][2], srp[2][4][2], gmp[2][4][2];

        // Z gate: zs = tanh(Z)*S_old
        gate_gemm(Sb, Wzp, Uz + l * 512, bz + l * 256, txS, q, c15, w, acc);
#pragma unroll
        for (int rb = 0; rb < 2; rb++)
#pragma unroll
            for (int cb = 0; cb < 4; cb++)
#pragma unroll
                for (int p = 0; p < 2; p++)
                    zsp[rb][cb][p] = pk2(
                        fast_tanh(acc[rb][cb][2 * p])     * upk(sreg[rb][cb][p], 0),
                        fast_tanh(acc[rb][cb][2 * p + 1]) * upk(sreg[rb][cb][p], 1));

        // R gate: sr = S_old*tanh(R)
        gate_gemm(Sb, Wrp, Ur + l * 512, br + l * 256, txS, q, c15, w, acc);
#pragma unroll
        for (int rb = 0; rb < 2; rb++)
#pragma unroll
            for (int cb = 0; cb < 4; cb++)
#pragma unroll
                for (int p = 0; p < 2; p++)
                    srp[rb][cb][p] = pk2(
                        upk(sreg[rb][cb][p], 0) * fast_tanh(acc[rb][cb][2 * p]),
                        upk(sreg[rb][cb][p], 1) * fast_tanh(acc[rb][cb][2 * p + 1]));

        // G gate (reads only S1b): 1 - tanh(G) = 2*rcp(e^{2G}+1)
        gate_gemm(S1b, Wgp, Ug + l * 512, bg + l * 256, txS, q, c15, w, acc);
#pragma unroll
        for (int rb = 0; rb < 2; rb++)
#pragma unroll
            for (int cb = 0; cb < 4; cb++)
#pragma unroll
                for (int p = 0; p < 2; p++)
                    gmp[rb][cb][p] = pk2(2.0f * rcp_1pe2x(acc[rb][cb][2 * p]),
                                         2.0f * rcp_1pe2x(acc[rb][cb][2 * p + 1]));

        __syncthreads();   // B1: all Sb reads (Z,R A-frags) done
#pragma unroll
        for (int rb = 0; rb < 2; rb++)
#pragma unroll
            for (int cb = 0; cb < 4; cb++) {
                int col = (w * 4 + cb) * 16 + c15;
#pragma unroll
                for (int p = 0; p < 2; p++) {
                    Sb[sw_off(rb * 16 + q * 4 + 2 * p,     col)] = (short)(srp[rb][cb][p] & 0xFFFFu);
                    Sb[sw_off(rb * 16 + q * 4 + 2 * p + 1, col)] = (short)(srp[rb][cb][p] >> 16);
                }
            }
        __syncthreads();   // B2: Sb = S*R visible

        // H gate (reads Sb = S*R)
        gate_gemm(Sb, Whp, Uh + l * 512, bh + l * 256, txS, q, c15, w, acc);

        // S_new = (1-G)*tanh(H) + zs  (no Sb access here)
#pragma unroll
        for (int rb = 0; rb < 2; rb++)
#pragma unroll
            for (int cb = 0; cb < 4; cb++)
#pragma unroll
                for (int p = 0; p < 2; p++) {
                    float sn0 = fmaf(upk(gmp[rb][cb][p], 0),
                                     fast_tanh(acc[rb][cb][2 * p]),
                                     upk(zsp[rb][cb][p], 0));
                    float sn1 = fmaf(upk(gmp[rb][cb][p], 1),
                                     fast_tanh(acc[rb][cb][2 * p + 1]),
                                     upk(zsp[rb][cb][p], 1));
                    srp[rb][cb][p] = pk2(sn0, sn1);
                }

        __syncthreads();   // B3: all H A-frag reads of Sb done
#pragma unroll
        for (int rb = 0; rb < 2; rb++)
#pragma unroll
            for (int cb = 0; cb < 4; cb++) {
                int col = (w * 4 + cb) * 16 + c15;
#pragma unroll
                for (int p = 0; p < 2; p++) {
                    Sb[sw_off(rb * 16 + q * 4 + 2 * p,     col)] = (short)(srp[rb][cb][p] & 0xFFFFu);
                    Sb[sw_off(rb * 16 + q * 4 + 2 * p + 1, col)] = (short)(srp[rb][cb][p] >> 16);
                    sreg[rb][cb][p] = srp[rb][cb][p];
                }
            }
        __syncthreads();   // B4: new S visible
    }

    // ---- out = S @ Wf + bf : 8 threads/row, vectorized LDS reads ----
    {
        int row = tid >> 3;
        int seg = tid & 7;
        float sum = 0.0f;
#pragma unroll
        for (int j = 0; j < 4; j++) {
            int ch = seg * 4 + j;
            bf16x8 sv = *(const bf16x8*)(Sb + row * 256 + (((ch ^ row) & 31) << 3));
            float4 wa = *(const float4*)(Wf + ch * 8);
            float4 wb = *(const float4*)(Wf + ch * 8 + 4);
            sum += bf2f(sv[0]) * wa.x + bf2f(sv[1]) * wa.y + bf2f(sv[2]) * wa.z + bf2f(sv[3]) * wa.w
                 + bf2f(sv[4]) * wb.x + bf2f(sv[5]) * wb.y + bf2f(sv[6]) * wb.z + bf2f(sv[7]) * wb.w;
        }
        sum += __shfl_down(sum, 4, 8);
        sum += __shfl_down(sum, 2, 8);
        sum += __shfl_down(sum, 1, 8);
        if (seg == 0) out[m0 + row] = sum + bfp[0];
    }
}

extern "C" void kernel_launch(void* const* d_in, const int* in_sizes, int n_in,
                              void* d_out, int out_size, void* d_ws, size_t ws_size,
                              hipStream_t stream) {
    const float* T  = (const float*)d_in[0];
    const float* X  = (const float*)d_in[1];
    const float* W0 = (const float*)d_in[2];
    const float* b0 = (const float*)d_in[3];
    const float* Uz = (const float*)d_in[4];
    const float* Ug = (const float*)d_in[5];
    const float* Ur = (const float*)d_in[6];
    const float* Uh = (const float*)d_in[7];
    const float* Wz = (const float*)d_in[8];
    const float* Wg = (const float*)d_in[9];
    const float* Wr = (const float*)d_in[10];
    const float* Wh = (const float*)d_in[11];
    const float* bz = (const float*)d_in[12];
    const float* bg = (const float*)d_in[13];
    const float* br = (const float*)d_in[14];
    const float* bh = (const float*)d_in[15];
    const float* Wf = (const float*)d_in[16];
    const float* bfp= (const float*)d_in[17];
    float* out = (float*)d_out;
    short* Wp = (short*)d_ws;           // 12*65536 bf16 = 1.5 MB
    const int N = in_sizes[0];

    pack_w<<<(12 * 65536) / 256, 256, 0, stream>>>(Wz, Wg, Wr, Wh, Wp);
    dgm_main<<<N / 32, 256, 0, stream>>>(T, X, W0, b0, Uz, Ug, Ur, Uh,
                                         bz, bg, br, bh, Wf, bfp, Wp, out);
}

// Round 3
// 408.916 us; speedup vs baseline: 2.7337x; 2.7337x over previous
//
#include <hip/hip_runtime.h>

// DGM forward, MI355X. bf16 MFMA 16x16x32, fp32 accum, fp32 tanh.
// R8: occupancy via SMALLER WAVE TILE, not launch-bound pressure.
//     R7 evidence: (256,3) => 84 VGPR + 500MB scratch => working set of the
//     32x64 wave tile needs ~2-wave budget. So: 512 threads/WG, 8 waves,
//     wave w owns cols [w*32, w*32+32): acc[2][2]=16, state arrays halved.
//     __launch_bounds__(512,4): 128 regs/wave budget -> 4 waves/SIMD,
//     2 WGs/CU (keeps cross-WG barrier overlap), LDS 2x33KB fits.
//     Schedule = proven R5 4-barrier structure; VALU cuts from R6 kept
//     (v_cvt_pk_bf16_f32, exp2-direct tanh, G-gate 1-tanh=2*rcp).
//     NEW: s_setprio(1) around MFMA cluster (T5; two independent WGs/CU at
//     different phases = role diversity).
//
// MFMA 16x16x32 layouts (ln = lane, q = ln>>4, c15 = ln&15):
//  A-frag: lane holds A[m=c15][k=kb*32+q*8+i], i=0..7
//  B-frag: lane holds B[k=kb*32+q*8+i][n=cblk*16+c15]
//  C/D:    lane holds C[row=q*4+ii][col=c15]
// W packed (d_ws) B-frag order per matrix: idx = (((cblk*8+kb)*64+ln)*8+i)
//  (cblk = global 16-col block 0..15; here cblk = w*2+cb, w=0..7, cb=0..1)
// LDS state swizzle: elem(r,k) -> r*256 + (((k>>3)^r)&31)*8 + (k&7)

typedef __attribute__((ext_vector_type(8))) short bf16x8;
typedef __attribute__((ext_vector_type(4))) float f32x4;

#if __has_builtin(__builtin_amdgcn_exp2f)
#define EXP2F(x) __builtin_amdgcn_exp2f(x)
#else
#define EXP2F(x) __expf((x) * 0.6931471805599453f)
#endif

__device__ __forceinline__ short f2bf(float f) {
    unsigned u = __float_as_uint(f);
    unsigned r = (u + 0x7FFFu + ((u >> 16) & 1u)) >> 16;
    return (short)r;
}
__device__ __forceinline__ float bf2f(short h) {
    return __uint_as_float(((unsigned)(unsigned short)h) << 16);
}
// packed bf16 pair via HW convert (RNE, same rounding as f2bf)
__device__ __forceinline__ unsigned cvtpk(float lo, float hi) {
    unsigned r;
    asm("v_cvt_pk_bf16_f32 %0, %1, %2" : "=v"(r) : "v"(lo), "v"(hi));
    return r;
}
// rcp(1 + e^{2x}); tanh(x) = 1 - 2*this; 1 - tanh(x) = 2*this
__device__ __forceinline__ float rcp_1pe2x(float x) {
    float e = EXP2F(x * 2.8853900817779268f);   // 2*log2(e)
    return __builtin_amdgcn_rcpf(e + 1.0f);
}
__device__ __forceinline__ float fast_tanh(float x) {
    return fmaf(-2.0f, rcp_1pe2x(x), 1.0f);
}
__device__ __forceinline__ int sw_off(int r, int k) {
    return r * 256 + ((((k >> 3) ^ r) & 31) << 3) + (k & 7);
}
__device__ __forceinline__ unsigned pk2(float a, float b) { return cvtpk(a, b); }
__device__ __forceinline__ float upk(unsigned p, int hi) {
    return __uint_as_float(hi ? (p & 0xFFFF0000u) : (p << 16));
}

// ---------------- pack weights fp32 -> bf16, B-frag order ----------------
__global__ void pack_w(const float* __restrict__ Wz, const float* __restrict__ Wg,
                       const float* __restrict__ Wr, const float* __restrict__ Wh,
                       short* __restrict__ out) {
    int idx = blockIdx.x * 256 + threadIdx.x;   // 12*65536 threads
    int mat = idx >> 16;                        // 0..11 = l*4+g
    int e   = idx & 65535;
    int l = mat >> 2, g = mat & 3;
    int i  = e & 7;
    int ln = (e >> 3) & 63;
    int kb = (e >> 9) & 7;
    int c  = e >> 12;
    int k = kb * 32 + (ln >> 4) * 8 + i;
    int n = c * 16 + (ln & 15);
    const float* W = (g == 0) ? Wz : (g == 1) ? Wg : (g == 2) ? Wr : Wh;
    out[idx] = f2bf(W[l * 65536 + k * 256 + n]);
}

// ---------------- one gate GEMM: acc = bias + X@U + In@W ----------------
// wave tile: 32 rows x 32 cols -> acc[2][2]
__device__ __forceinline__ void gate_gemm(const short* __restrict__ In,   // LDS [32][256] swizzled
                                          const short* __restrict__ Wm,   // packed bf16 65536
                                          const float* __restrict__ U,    // [2][256] fp32
                                          const float* __restrict__ bias, // [256]
                                          const float2* __restrict__ txS, // LDS [32]
                                          int q, int c15, int w,
                                          f32x4 acc[2][2]) {
    float2 tx[8];
#pragma unroll
    for (int rb = 0; rb < 2; rb++)
#pragma unroll
        for (int ii = 0; ii < 4; ii++) tx[rb * 4 + ii] = txS[rb * 16 + q * 4 + ii];
#pragma unroll
    for (int cb = 0; cb < 2; cb++) {
        int col = (w * 2 + cb) * 16 + c15;
        float u0 = U[col], u1 = U[256 + col], bb = bias[col];
#pragma unroll
        for (int rb = 0; rb < 2; rb++)
#pragma unroll
            for (int ii = 0; ii < 4; ii++)
                acc[rb][cb][ii] = bb + tx[rb * 4 + ii].x * u0 + tx[rb * 4 + ii].y * u1;
    }
    __builtin_amdgcn_s_setprio(1);
#pragma unroll
    for (int kb = 0; kb < 8; kb++) {
        bf16x8 a[2];
#pragma unroll
        for (int rb = 0; rb < 2; rb++) {
            int r = rb * 16 + c15;
            a[rb] = *(const bf16x8*)(In + r * 256 + ((((kb * 4 + q) ^ r) & 31) << 3));
        }
#pragma unroll
        for (int cb = 0; cb < 2; cb++) {
            bf16x8 b = *(const bf16x8*)(Wm + ((((w * 2 + cb) * 8 + kb) * 64 + (q * 16 + c15)) << 3));
#pragma unroll
            for (int rb = 0; rb < 2; rb++)
                acc[rb][cb] = __builtin_amdgcn_mfma_f32_16x16x32_bf16(a[rb], b, acc[rb][cb], 0, 0, 0);
        }
    }
    __builtin_amdgcn_s_setprio(0);
}

// ---------------- main kernel: 32 rows/WG, 512 threads (8 waves) ----------------
__global__ __launch_bounds__(512, 4)
void dgm_main(const float* __restrict__ T, const float* __restrict__ X,
              const float* __restrict__ W0, const float* __restrict__ b0,
              const float* __restrict__ Uz, const float* __restrict__ Ug,
              const float* __restrict__ Ur, const float* __restrict__ Uh,
              const float* __restrict__ bz, const float* __restrict__ bg,
              const float* __restrict__ br, const float* __restrict__ bh,
              const float* __restrict__ Wf, const float* __restrict__ bfp,
              const short* __restrict__ Wp, float* __restrict__ out) {
    __shared__ __align__(16) short Sb[8192];    // 16 KB: S (holds S*R mid-layer)
    __shared__ __align__(16) short S1b[8192];   // 16 KB: S1, immutable
    __shared__ float2 txS[32];

    const int tid = threadIdx.x;
    const int w   = tid >> 6;        // 0..7
    const int ln  = tid & 63;
    const int q   = ln >> 4;
    const int c15 = ln & 15;
    const int m0  = blockIdx.x * 32;

    if (tid < 32) txS[tid] = make_float2(T[m0 + tid], X[m0 + tid]);
    __syncthreads();

    // ---- S1 = tanh(X@W0 + b0); S = S1. 512 thr: (col, half of rows) each ----
    {
        int col  = tid & 255;
        int half = tid >> 8;         // 0/1 -> rows [half*16, half*16+16)
        float w00 = W0[col], w01 = W0[256 + col], bb = b0[col];
#pragma unroll 4
        for (int rr = 0; rr < 16; rr++) {
            int r = half * 16 + rr;
            float2 tx = txS[r];
            short v = f2bf(fast_tanh(tx.x * w00 + tx.y * w01 + bb));
            int off = sw_off(r, col);
            S1b[off] = v;
            Sb[off]  = v;
        }
    }
    __syncthreads();

    // register mirror of this thread's owned S elements (C-layout), packed bf16
    unsigned sreg[2][2][2];
#pragma unroll
    for (int rb = 0; rb < 2; rb++)
#pragma unroll
        for (int cb = 0; cb < 2; cb++) {
            int col = (w * 2 + cb) * 16 + c15;
#pragma unroll
            for (int p = 0; p < 2; p++) {
                unsigned lo = (unsigned short)Sb[sw_off(rb * 16 + q * 4 + 2 * p,     col)];
                unsigned hi = (unsigned short)Sb[sw_off(rb * 16 + q * 4 + 2 * p + 1, col)];
                sreg[rb][cb][p] = lo | (hi << 16);
            }
        }

    // ---- layers ----
    for (int l = 0; l < 3; l++) {
        const short* Wzp = Wp + (l * 4 + 0) * 65536;
        const short* Wgp = Wp + (l * 4 + 1) * 65536;
        const short* Wrp = Wp + (l * 4 + 2) * 65536;
        const short* Whp = Wp + (l * 4 + 3) * 65536;

        f32x4 acc[2][2];
        unsigned zsp[2][2][2], srp[2][2][2], gmp[2][2][2];

        // Z gate: zs = tanh(Z)*S_old
        gate_gemm(Sb, Wzp, Uz + l * 512, bz + l * 256, txS, q, c15, w, acc);
#pragma unroll
        for (int rb = 0; rb < 2; rb++)
#pragma unroll
            for (int cb = 0; cb < 2; cb++)
#pragma unroll
                for (int p = 0; p < 2; p++)
                    zsp[rb][cb][p] = pk2(
                        fast_tanh(acc[rb][cb][2 * p])     * upk(sreg[rb][cb][p], 0),
                        fast_tanh(acc[rb][cb][2 * p + 1]) * upk(sreg[rb][cb][p], 1));

        // R gate: sr = S_old*tanh(R)
        gate_gemm(Sb, Wrp, Ur + l * 512, br + l * 256, txS, q, c15, w, acc);
#pragma unroll
        for (int rb = 0; rb < 2; rb++)
#pragma unroll
            for (int cb = 0; cb < 2; cb++)
#pragma unroll
                for (int p = 0; p < 2; p++)
                    srp[rb][cb][p] = pk2(
                        upk(sreg[rb][cb][p], 0) * fast_tanh(acc[rb][cb][2 * p]),
                        upk(sreg[rb][cb][p], 1) * fast_tanh(acc[rb][cb][2 * p + 1]));

        // G gate (reads only S1b): 1 - tanh(G) = 2*rcp(e^{2G}+1)
        gate_gemm(S1b, Wgp, Ug + l * 512, bg + l * 256, txS, q, c15, w, acc);
#pragma unroll
        for (int rb = 0; rb < 2; rb++)
#pragma unroll
            for (int cb = 0; cb < 2; cb++)
#pragma unroll
                for (int p = 0; p < 2; p++)
                    gmp[rb][cb][p] = pk2(2.0f * rcp_1pe2x(acc[rb][cb][2 * p]),
                                         2.0f * rcp_1pe2x(acc[rb][cb][2 * p + 1]));

        __syncthreads();   // B1: all Sb reads (Z,R A-frags) done
#pragma unroll
        for (int rb = 0; rb < 2; rb++)
#pragma unroll
            for (int cb = 0; cb < 2; cb++) {
                int col = (w * 2 + cb) * 16 + c15;
#pragma unroll
                for (int p = 0; p < 2; p++) {
                    Sb[sw_off(rb * 16 + q * 4 + 2 * p,     col)] = (short)(srp[rb][cb][p] & 0xFFFFu);
                    Sb[sw_off(rb * 16 + q * 4 + 2 * p + 1, col)] = (short)(srp[rb][cb][p] >> 16);
                }
            }
        __syncthreads();   // B2: Sb = S*R visible

        // H gate (reads Sb = S*R)
        gate_gemm(Sb, Whp, Uh + l * 512, bh + l * 256, txS, q, c15, w, acc);

        // S_new = (1-G)*tanh(H) + zs  (no Sb access here)
#pragma unroll
        for (int rb = 0; rb < 2; rb++)
#pragma unroll
            for (int cb = 0; cb < 2; cb++)
#pragma unroll
                for (int p = 0; p < 2; p++) {
                    float sn0 = fmaf(upk(gmp[rb][cb][p], 0),
                                     fast_tanh(acc[rb][cb][2 * p]),
                                     upk(zsp[rb][cb][p], 0));
                    float sn1 = fmaf(upk(gmp[rb][cb][p], 1),
                                     fast_tanh(acc[rb][cb][2 * p + 1]),
                                     upk(zsp[rb][cb][p], 1));
                    srp[rb][cb][p] = pk2(sn0, sn1);
                }

        __syncthreads();   // B3: all H A-frag reads of Sb done
#pragma unroll
        for (int rb = 0; rb < 2; rb++)
#pragma unroll
            for (int cb = 0; cb < 2; cb++) {
                int col = (w * 2 + cb) * 16 + c15;
#pragma unroll
                for (int p = 0; p < 2; p++) {
                    Sb[sw_off(rb * 16 + q * 4 + 2 * p,     col)] = (short)(srp[rb][cb][p] & 0xFFFFu);
                    Sb[sw_off(rb * 16 + q * 4 + 2 * p + 1, col)] = (short)(srp[rb][cb][p] >> 16);
                    sreg[rb][cb][p] = srp[rb][cb][p];
                }
            }
        __syncthreads();   // B4: new S visible
    }

    // ---- out = S @ Wf + bf : 16 threads/row, vectorized LDS reads ----
    {
        int row = tid >> 4;          // 0..31
        int seg = tid & 15;          // 16 threads per row
        float sum = 0.0f;
#pragma unroll
        for (int j = 0; j < 2; j++) {
            int ch = seg * 2 + j;    // 0..31 (8-elem chunks)
            bf16x8 sv = *(const bf16x8*)(Sb + row * 256 + (((ch ^ row) & 31) << 3));
            float4 wa = *(const float4*)(Wf + ch * 8);
            float4 wb = *(const float4*)(Wf + ch * 8 + 4);
            sum += bf2f(sv[0]) * wa.x + bf2f(sv[1]) * wa.y + bf2f(sv[2]) * wa.z + bf2f(sv[3]) * wa.w
                 + bf2f(sv[4]) * wb.x + bf2f(sv[5]) * wb.y + bf2f(sv[6]) * wb.z + bf2f(sv[7]) * wb.w;
        }
        sum += __shfl_down(sum, 8, 16);
        sum += __shfl_down(sum, 4, 16);
        sum += __shfl_down(sum, 2, 16);
        sum += __shfl_down(sum, 1, 16);
        if (seg == 0) out[m0 + row] = sum + bfp[0];
    }
}

extern "C" void kernel_launch(void* const* d_in, const int* in_sizes, int n_in,
                              void* d_out, int out_size, void* d_ws, size_t ws_size,
                              hipStream_t stream) {
    const float* T  = (const float*)d_in[0];
    const float* X  = (const float*)d_in[1];
    const float* W0 = (const float*)d_in[2];
    const float* b0 = (const float*)d_in[3];
    const float* Uz = (const float*)d_in[4];
    const float* Ug = (const float*)d_in[5];
    const float* Ur = (const float*)d_in[6];
    const float* Uh = (const float*)d_in[7];
    const float* Wz = (const float*)d_in[8];
    const float* Wg = (const float*)d_in[9];
    const float* Wr = (const float*)d_in[10];
    const float* Wh = (const float*)d_in[11];
    const float* bz = (const float*)d_in[12];
    const float* bg = (const float*)d_in[13];
    const float* br = (const float*)d_in[14];
    const float* bh = (const float*)d_in[15];
    const float* Wf = (const float*)d_in[16];
    const float* bfp= (const float*)d_in[17];
    float* out = (float*)d_out;
    short* Wp = (short*)d_ws;           // 12*65536 bf16 = 1.5 MB
    const int N = in_sizes[0];

    pack_w<<<(12 * 65536) / 256, 256, 0, stream>>>(Wz, Wg, Wr, Wh, Wp);
    dgm_main<<<N / 32, 512, 0, stream>>>(T, X, W0, b0, Uz, Ug, Ur, Uh,
                                         bz, bg, br, bh, Wf, bfp, Wp, out);
}